// Round 1
// baseline (406.928 us; speedup 1.0000x reference)
//
#include <hip/hip_runtime.h>

#define BATCH 8192
#define DIM   2048   // IN_DIM == OUT_DIM
#define DEPTH 5

#define TM 128
#define TN 128
#define BK 32
#define KDIM 2048

typedef short bf16x8_t __attribute__((ext_vector_type(8)));
typedef float f32x4_t  __attribute__((ext_vector_type(4)));

// ---- bf16 split helpers (RNE, bit-manip: no __bf16 type dependence) ----
__device__ __forceinline__ unsigned short f2bf(float f) {
  unsigned u = __float_as_uint(f);
  u += 0x7fffu + ((u >> 16) & 1u);
  return (unsigned short)(u >> 16);
}
__device__ __forceinline__ float bf2f(unsigned short h) {
  return __uint_as_float(((unsigned)h) << 16);
}

// ============================================================================
// Kernel 1: bias2[j] = b[j] + (1/2048) * prod_d cos(hdw[d, j, 0])^2
// (the scan preserves uniformity along axis=1, so rolls cancel; phases vanish
//  under |.|^2 -> hd[j] = |s0 * prod cos|^2)
// ============================================================================
__global__ void prep_bias_kernel(const float* __restrict__ hdw,
                                 const float* __restrict__ bias,
                                 float* __restrict__ bias2) {
  int j = blockIdx.x * 256 + threadIdx.x;
  float p = 1.0f;
#pragma unroll
  for (int d = 0; d < DEPTH; ++d) {
    p *= cosf(hdw[(size_t)d * DIM * DIM + (size_t)j * DIM]);
  }
  bias2[j] = bias[j] + p * p * (1.0f / 2048.0f);
}

// ============================================================================
// Kernel 2: split x (8192x2048 f32) -> x_hi, x_lo (bf16 stored as ushort)
// ============================================================================
__global__ void split_x_kernel(const float4* __restrict__ x,
                               ushort4* __restrict__ xhi,
                               ushort4* __restrict__ xlo) {
  size_t i = (size_t)blockIdx.x * 256 + threadIdx.x;
  float4 v = x[i];
  ushort4 h, l;
  h.x = f2bf(v.x); l.x = f2bf(v.x - bf2f(h.x));
  h.y = f2bf(v.y); l.y = f2bf(v.y - bf2f(h.y));
  h.z = f2bf(v.z); l.z = f2bf(v.z - bf2f(h.z));
  h.w = f2bf(v.w); l.w = f2bf(v.w - bf2f(h.w));
  xhi[i] = h;
  xlo[i] = l;
}

// ============================================================================
// Kernel 3: W (K x N row-major f32) -> W^T hi/lo (N x K row-major bf16)
// LDS tile transpose so both global read and write are coalesced.
// ============================================================================
__global__ void split_wT_kernel(const float* __restrict__ W,
                                unsigned short* __restrict__ whi,
                                unsigned short* __restrict__ wlo) {
  __shared__ float tile[32][33];
  const int tx = threadIdx.x;  // 0..31
  const int ty = threadIdx.y;  // 0..7
  const int n0 = blockIdx.x * 32;
  const int k0 = blockIdx.y * 32;
#pragma unroll
  for (int r = 0; r < 32; r += 8)
    tile[ty + r][tx] = W[(size_t)(k0 + ty + r) * DIM + n0 + tx];
  __syncthreads();
#pragma unroll
  for (int r = 0; r < 32; r += 8) {
    float v = tile[tx][ty + r];                 // = W[k0+tx][n0+ty+r]
    unsigned short h = f2bf(v);
    unsigned short l = f2bf(v - bf2f(h));
    size_t o = (size_t)(n0 + ty + r) * DIM + k0 + tx;  // wT[n][k]
    whi[o] = h;
    wlo[o] = l;
  }
}

// ============================================================================
// Kernel 4: C = A@W via bf16x3 MFMA; out = tanh(C + bias2)
// 128x128 tile, BK=32, 4 waves (2x2), each wave 64x64 = 4x4 of 16x16x32 MFMA.
// Staging via global_load_lds width=16 (wave-uniform LDS base + lane*16).
// ============================================================================
__device__ __forceinline__ void stage_tile(const unsigned short* gbase,
                                           unsigned short* s, int wave, int lane) {
  // tile is 128 rows x 32 cols bf16, row-major in LDS; global row stride = KDIM
#pragma unroll
  for (int r = 0; r < 2; ++r) {
    int slot = r * 256 + wave * 64 + lane;               // 512 slots x 8 bf16
    const unsigned short* gp = gbase + (slot >> 2) * KDIM + (slot & 3) * 8;
    unsigned short* lp = s + (r * 256 + wave * 64) * 8;  // wave-uniform base
    __builtin_amdgcn_global_load_lds(
        (const __attribute__((address_space(1))) void*)gp,
        (__attribute__((address_space(3))) void*)lp, 16, 0, 0);
  }
}

__global__ __launch_bounds__(256) void gemm_x3_kernel(
    const unsigned short* __restrict__ Ahi, const unsigned short* __restrict__ Alo,
    const unsigned short* __restrict__ Bhi, const unsigned short* __restrict__ Blo,
    const float* __restrict__ bias2, float* __restrict__ out) {
  __shared__ __attribute__((aligned(16))) unsigned short sAhi[TM * BK];
  __shared__ __attribute__((aligned(16))) unsigned short sAlo[TM * BK];
  __shared__ __attribute__((aligned(16))) unsigned short sBhi[TN * BK];
  __shared__ __attribute__((aligned(16))) unsigned short sBlo[TN * BK];

  const int tid  = threadIdx.x;
  const int wave = tid >> 6;
  const int lane = tid & 63;
  const int bm = blockIdx.x;   // consecutive bm share bn -> W strip stays L2-hot
  const int bn = blockIdx.y;
  const int wm = wave >> 1, wn = wave & 1;
  const int l15 = lane & 15, kl = lane >> 4;

  const unsigned short* agh = Ahi + (size_t)bm * TM * KDIM;
  const unsigned short* agl = Alo + (size_t)bm * TM * KDIM;
  const unsigned short* bgh = Bhi + (size_t)bn * TN * KDIM;
  const unsigned short* bgl = Blo + (size_t)bn * TN * KDIM;

  int aidx[4], bidx[4];
#pragma unroll
  for (int i = 0; i < 4; ++i) {
    aidx[i] = (wm * 64 + i * 16 + l15) * BK + kl * 8;
    bidx[i] = (wn * 64 + i * 16 + l15) * BK + kl * 8;
  }

  const f32x4_t vzero = {0.f, 0.f, 0.f, 0.f};
  f32x4_t acc[4][4];
#pragma unroll
  for (int i = 0; i < 4; ++i)
#pragma unroll
    for (int j = 0; j < 4; ++j) acc[i][j] = vzero;

  for (int kt = 0; kt < KDIM / BK; ++kt) {
    if (kt) __syncthreads();  // all waves done reading previous LDS tiles
    const int ko = kt * BK;
    stage_tile(agh + ko, sAhi, wave, lane);
    stage_tile(agl + ko, sAlo, wave, lane);
    stage_tile(bgh + ko, sBhi, wave, lane);
    stage_tile(bgl + ko, sBlo, wave, lane);
    asm volatile("s_waitcnt vmcnt(0)" ::: "memory");
    __syncthreads();

    bf16x8_t ah[4], al[4], bh[4], bl[4];
#pragma unroll
    for (int i = 0; i < 4; ++i) {
      ah[i] = *(const bf16x8_t*)(sAhi + aidx[i]);
      al[i] = *(const bf16x8_t*)(sAlo + aidx[i]);
      bh[i] = *(const bf16x8_t*)(sBhi + bidx[i]);
      bl[i] = *(const bf16x8_t*)(sBlo + bidx[i]);
    }
#pragma unroll
    for (int i = 0; i < 4; ++i)
#pragma unroll
      for (int j = 0; j < 4; ++j) {
        acc[i][j] = __builtin_amdgcn_mfma_f32_16x16x32_bf16(ah[i], bh[j], acc[i][j], 0, 0, 0);
        acc[i][j] = __builtin_amdgcn_mfma_f32_16x16x32_bf16(ah[i], bl[j], acc[i][j], 0, 0, 0);
        acc[i][j] = __builtin_amdgcn_mfma_f32_16x16x32_bf16(al[i], bh[j], acc[i][j], 0, 0, 0);
      }
  }

  // Epilogue: C/D layout col = lane&15, row = (lane>>4)*4 + reg  [m89/m91]
  const int orow0 = bm * TM + wm * 64;
  const int ocol0 = bn * TN + wn * 64;
#pragma unroll
  for (int j = 0; j < 4; ++j) {
    const int col = ocol0 + j * 16 + l15;
    const float b2 = bias2[col];
#pragma unroll
    for (int i = 0; i < 4; ++i) {
      const int row = orow0 + i * 16 + kl * 4;
#pragma unroll
      for (int r = 0; r < 4; ++r) {
        float z = acc[i][j][r] + b2;
        // tanh(z) = 1 - 2/(exp(2z)+1); exact limits at +-inf via ieee inf/0
        float e = __expf(2.0f * z);
        out[(size_t)(row + r) * DIM + col] = 1.0f - 2.0f / (e + 1.0f);
      }
    }
  }
}

// ============================================================================
extern "C" void kernel_launch(void* const* d_in, const int* in_sizes, int n_in,
                              void* d_out, int out_size, void* d_ws, size_t ws_size,
                              hipStream_t stream) {
  const float* x   = (const float*)d_in[0];
  const float* hdw = (const float*)d_in[1];
  const float* W   = (const float*)d_in[2];
  const float* b   = (const float*)d_in[3];
  float* out = (float*)d_out;

  // workspace layout (needs ~80.01 MB)
  char* ws = (char*)d_ws;
  float*          bias2 = (float*)ws;                               // 8 KB
  unsigned short* xhi   = (unsigned short*)(ws + 8192);             // 32 MB
  unsigned short* xlo   = xhi + (size_t)BATCH * DIM;                // 32 MB
  unsigned short* wThi  = xlo + (size_t)BATCH * DIM;                // 8 MB
  unsigned short* wTlo  = wThi + (size_t)DIM * DIM;                 // 8 MB

  prep_bias_kernel<<<DIM / 256, 256, 0, stream>>>(hdw, b, bias2);
  split_x_kernel<<<(BATCH * DIM / 4) / 256, 256, 0, stream>>>(
      (const float4*)x, (ushort4*)xhi, (ushort4*)xlo);
  split_wT_kernel<<<dim3(DIM / 32, DIM / 32), dim3(32, 8), 0, stream>>>(W, wThi, wTlo);
  gemm_x3_kernel<<<dim3(BATCH / TM, DIM / TN), 256, 0, stream>>>(
      xhi, xlo, wThi, wTlo, bias2, out);
}